// Round 20
// baseline (379.772 us; speedup 1.0000x reference)
//
#include <hip/hip_runtime.h>

// GeniePath: 2x GAT(H=1,D=128) + LSTM step. N=100000, E=1600000, D=OUT=128.
// Inputs f32, output f32: [h1 (N*128)] [h1 (N*128)] [c1 (N*128)]
//
// Round 19->20 (agg only): half-wave edge parallelism. Each 32-lane half
// processes alternate edges; each lane covers 4 cols via one 8B load
// (was 2 cols / 4B). Final shfl_xor(32) merges halves. ~25% fewer issue
// slots, half the load instructions, 4 loads in flight.
//
// d_ws: rst bf16 (25.6MB) + WTb (256KB) + Wswz (32KB).
// d_out (153.6MB) holds transients, all dead before lstm_mfma rewrites it.

#define D 128
#define NEG_SLOPE 0.2f
#define SM_SHIFT 8.0f
#define CSH 9            // coarse bucket = node >> CSH (512 nodes)
#define SRCB 18          // src bits in packed pair (N <= 262144)
#define PA_CHUNK 16384

typedef short bf16x8 __attribute__((ext_vector_type(8)));
typedef float f32x4 __attribute__((ext_vector_type(4)));
typedef unsigned short ushort8v __attribute__((ext_vector_type(8)));
typedef unsigned int uintv2 __attribute__((ext_vector_type(2)));

__device__ __forceinline__ unsigned short f2bf(float x) {
    unsigned int b = __float_as_uint(x);
    b += 0x7fff + ((b >> 16) & 1);
    return (unsigned short)(b >> 16);
}
__device__ __forceinline__ float bf2f(unsigned short u) {
    union { unsigned int i; float f; } x;
    x.i = ((unsigned int)u) << 16;
    return x.f;
}
__device__ __forceinline__ float fsig(float x) {
    return 1.f / (1.f + __expf(-x));
}
__device__ __forceinline__ float ftanh(float x) {
    x = fminf(15.f, fmaxf(-15.f, x));
    float t = __expf(2.f * x);
    return (t - 1.f) / (t + 1.f);
}

// ---------------- weight swizzles ----------------
__global__ void wprep_feat_kernel(const float* __restrict__ W,
                                  unsigned short* __restrict__ Wswz) {
    int t = blockIdx.x * 256 + threadIdx.x;
    if (t >= 8 * 4 * 64) return;
    int ct = t >> 8, ks = (t >> 6) & 3, lane = t & 63;
    int col = ct * 16 + (lane & 15);
    int k0 = ks * 32 + ((lane >> 4) << 3);
#pragma unroll
    for (int i = 0; i < 8; ++i)
        Wswz[(size_t)t * 8 + i] = f2bf(W[(k0 + i) * D + col]);
}

__global__ void wprep_lstm_kernel(const float* __restrict__ W_ih,
                                  const float* __restrict__ W_hh,
                                  unsigned short* __restrict__ WTb) {
    int t = blockIdx.x * 256 + threadIdx.x;
    if (t >= 32 * 8 * 64) return;
    int ct = t >> 9, ks = (t >> 6) & 7, lane = t & 63;
    int col = ct * 16 + (lane & 15);
    int k0 = ks * 32 + ((lane >> 4) << 3);
#pragma unroll
    for (int i = 0; i < 8; ++i) {
        int k = k0 + i;
        float v = (k < 128) ? W_ih[col * 128 + k] : W_hh[col * 128 + (k - 128)];
        WTb[(size_t)t * 8 + i] = f2bf(v);
    }
}

// ---- feat = x @ W via MFMA; bf16 out; fused el/er ----
#define FM 32
template <bool BF>
__global__ __launch_bounds__(256) void feat_mfma_kernel(const void* __restrict__ xin_,
                                                        const unsigned short* __restrict__ Wswz,
                                                        unsigned short* __restrict__ feat,
                                                        const float* __restrict__ al,
                                                        const float* __restrict__ ar,
                                                        float* __restrict__ el,
                                                        float* __restrict__ er, int N_) {
    __shared__ unsigned short sm[FM][136];
    int tid = threadIdx.x;
    int bn = blockIdx.x * FM;
    for (int idx = tid; idx < FM * 16; idx += 256) {
        int n = idx >> 4, q = idx & 15;
        int gn = bn + n;
        ushort8v u = (ushort8v)0;
        if (gn < N_) {
            if constexpr (BF) {
                u = *(const ushort8v*)((const unsigned short*)xin_ + (size_t)gn * D + q * 8);
            } else {
                const float* sp = (const float*)xin_ + (size_t)gn * D + q * 8;
                float4 a = ((const float4*)sp)[0];
                float4 b = ((const float4*)sp)[1];
                u[0] = f2bf(a.x); u[1] = f2bf(a.y); u[2] = f2bf(a.z); u[3] = f2bf(a.w);
                u[4] = f2bf(b.x); u[5] = f2bf(b.y); u[6] = f2bf(b.z); u[7] = f2bf(b.w);
            }
        }
        *(ushort8v*)&sm[n][q * 8] = u;
    }
    __syncthreads();
    int w = tid >> 6, l = tid & 63;
    f32x4 acc[2][2];
#pragma unroll
    for (int m = 0; m < 2; ++m)
#pragma unroll
        for (int p = 0; p < 2; ++p) acc[m][p] = (f32x4)0.f;
    int ar_ = l & 15, ak = (l >> 4) << 3;
#pragma unroll
    for (int ks = 0; ks < 4; ++ks) {
        bf16x8 a0 = *(const bf16x8*)&sm[ar_][ks * 32 + ak];
        bf16x8 a1 = *(const bf16x8*)&sm[16 + ar_][ks * 32 + ak];
#pragma unroll
        for (int p = 0; p < 2; ++p) {
            int ct = w * 2 + p;
            bf16x8 b = *(const bf16x8*)(Wswz + ((size_t)(ct * 4 + ks) * 64 + l) * 8);
            acc[0][p] = __builtin_amdgcn_mfma_f32_16x16x32_bf16(a0, b, acc[0][p], 0, 0, 0);
            acc[1][p] = __builtin_amdgcn_mfma_f32_16x16x32_bf16(a1, b, acc[1][p], 0, 0, 0);
        }
    }
    __syncthreads();
#pragma unroll
    for (int p = 0; p < 2; ++p) {
        int col = (w * 2 + p) * 16 + (l & 15);
#pragma unroll
        for (int m = 0; m < 2; ++m)
#pragma unroll
            for (int r = 0; r < 4; ++r) {
                int row = m * 16 + ((l >> 4) << 2) + r;
                sm[row][col] = f2bf(acc[m][p][r]);
            }
    }
    __syncthreads();
#pragma unroll
    for (int s = 0; s < 2; ++s) {
        int idx = tid + s * 256;
        int row = idx >> 4, q = idx & 15;
        int gn = bn + row;
        if (gn < N_)
            *(ushort8v*)(feat + (size_t)gn * D + q * 8) = *(const ushort8v*)&sm[row][q * 8];
    }
    {
        int row = w * 8 + (l >> 3);
        int c0 = (l & 7) * 16;
        int gn = bn + row;
        float pl = 0.f, pr = 0.f;
#pragma unroll
        for (int i = 0; i < 16; ++i) {
            float v = bf2f(sm[row][c0 + i]);
            pl += v * al[c0 + i];
            pr += v * ar[c0 + i];
        }
        pl += __shfl_xor(pl, 1); pr += __shfl_xor(pr, 1);
        pl += __shfl_xor(pl, 2); pr += __shfl_xor(pr, 2);
        pl += __shfl_xor(pl, 4); pr += __shfl_xor(pr, 4);
        if ((l & 7) == 0 && gn < N_) { el[gn] = pl; er[gn] = pr; }
    }
}

// ---------------- bucket-level CSR build ----------------
__global__ void zero_kernel(int* __restrict__ p, int n) {
    int i = blockIdx.x * 256 + threadIdx.x;
    if (i < n) p[i] = 0;
}

__global__ __launch_bounds__(256) void bhist_kernel(const int* __restrict__ dst0,
                                                    const int* __restrict__ dst1,
                                                    int* __restrict__ bcnt,
                                                    int E_, int N_, int nbuck) {
    __shared__ int cL[512];
    int tid = threadIdx.x;
    int c0 = blockIdx.x * PA_CHUNK;
    int e2 = 2 * E_;
    int cend = min(c0 + PA_CHUNK, e2);
    for (int t = tid; t < nbuck; t += 256) cL[t] = 0;
    __syncthreads();
    for (int i = c0 + tid; i < cend; i += 256) {
        int d = (i < E_) ? dst0[i] : (dst1[i - E_] + N_);
        atomicAdd(&cL[d >> CSH], 1);
    }
    __syncthreads();
    for (int t = tid; t < nbuck; t += 256) {
        int c = cL[t];
        if (c > 0) atomicAdd(&bcnt[t], c);
    }
}

__global__ __launch_bounds__(256) void bscan_kernel(const int* __restrict__ bcnt,
                                                    int* __restrict__ bbase,
                                                    int* __restrict__ bcur,
                                                    int nbuck, int e2) {
    __shared__ int sarr[256];
    int t = threadIdx.x;
    int v0 = (2 * t < nbuck) ? bcnt[2 * t] : 0;
    int v1 = (2 * t + 1 < nbuck) ? bcnt[2 * t + 1] : 0;
    sarr[t] = v0 + v1;
    __syncthreads();
    for (int off = 1; off < 256; off <<= 1) {
        int x = (t >= off) ? sarr[t - off] : 0;
        __syncthreads();
        sarr[t] += x;
        __syncthreads();
    }
    int excl = sarr[t] - (v0 + v1);
    if (2 * t < nbuck)     { bbase[2 * t] = excl;         bcur[2 * t] = excl; }
    if (2 * t + 1 < nbuck) { bbase[2 * t + 1] = excl + v0; bcur[2 * t + 1] = excl + v0; }
    if (t == 0) bbase[nbuck] = e2;
}

__global__ __launch_bounds__(256) void partA_kernel(const int* __restrict__ src0,
                                                    const int* __restrict__ src1,
                                                    const int* __restrict__ dst0,
                                                    const int* __restrict__ dst1,
                                                    int* __restrict__ bcur,
                                                    unsigned int* __restrict__ pbuf,
                                                    int E_, int N_, int nbuck) {
    __shared__ int cntL[512];
    __shared__ int baseL[512];
    int tid = threadIdx.x;
    int c0 = blockIdx.x * PA_CHUNK;
    int e2 = 2 * E_;
    int cend = min(c0 + PA_CHUNK, e2);
    for (int t = tid; t < nbuck; t += 256) cntL[t] = 0;
    __syncthreads();
    for (int i = c0 + tid; i < cend; i += 256) {
        int d = (i < E_) ? dst0[i] : (dst1[i - E_] + N_);
        atomicAdd(&cntL[d >> CSH], 1);
    }
    __syncthreads();
    for (int t = tid; t < nbuck; t += 256) {
        int c = cntL[t];
        baseL[t] = (c > 0) ? atomicAdd(&bcur[t], c) : 0;
        cntL[t] = 0;
    }
    __syncthreads();
    for (int i = c0 + tid; i < cend; i += 256) {
        int s, d;
        if (i < E_) { s = src0[i]; d = dst0[i]; }
        else        { s = src1[i - E_]; d = dst1[i - E_] + N_; }
        int bin = d >> CSH;
        int loc = atomicAdd(&cntL[bin], 1);
        pbuf[baseL[bin] + loc] = ((unsigned int)(d & ((1 << CSH) - 1)) << SRCB) | (unsigned int)s;
    }
}

__global__ __launch_bounds__(256) void partB2_kernel(const unsigned int* __restrict__ pbuf,
                                                     const int* __restrict__ bbase,
                                                     int* __restrict__ rowptr,
                                                     int* __restrict__ csrc,
                                                     int n2, int e2) {
    __shared__ int histL[1 << CSH];
    __shared__ int sarr[256];
    int b = blockIdx.x;
    int tid = threadIdx.x;
    int bstart = b << CSH;
    int nn = min(1 << CSH, n2 - bstart);
    int r0 = bbase[b], r1 = bbase[b + 1];
    for (int t = tid; t < nn; t += 256) histL[t] = 0;
    __syncthreads();
    for (int i = r0 + tid; i < r1; i += 256)
        atomicAdd(&histL[pbuf[i] >> SRCB], 1);
    __syncthreads();
    int v0 = (2 * tid < nn) ? histL[2 * tid] : 0;
    int v1 = (2 * tid + 1 < nn) ? histL[2 * tid + 1] : 0;
    sarr[tid] = v0 + v1;
    __syncthreads();
    for (int off = 1; off < 256; off <<= 1) {
        int x = (tid >= off) ? sarr[tid - off] : 0;
        __syncthreads();
        sarr[tid] += x;
        __syncthreads();
    }
    int excl = sarr[tid] - (v0 + v1);
    int p0 = r0 + excl, p1 = r0 + excl + v0;
    if (2 * tid < nn)     rowptr[bstart + 2 * tid] = p0;
    if (2 * tid + 1 < nn) rowptr[bstart + 2 * tid + 1] = p1;
    if (b == gridDim.x - 1 && tid == 0) rowptr[n2] = e2;
    __syncthreads();
    if (2 * tid < nn)     histL[2 * tid] = p0;
    if (2 * tid + 1 < nn) histL[2 * tid + 1] = p1;
    __syncthreads();
    for (int i = r0 + tid; i < r1; i += 256) {
        unsigned int pk = pbuf[i];
        int dl = (int)(pk >> SRCB);
        int s = (int)(pk & ((1u << SRCB) - 1));
        int pos = atomicAdd(&histL[dl], 1);
        csrc[pos] = s;
    }
}

// ---- fused softmax + aggregation: half-wave edge parallelism ----
// lane = half*32 + hl; half h processes edges j+h of each pair; lane covers
// cols [hl*4, hl*4+4) via one 8B load. shfl_xor(32) merges halves at end.
__global__ __launch_bounds__(256) void agg_kernel(const int* __restrict__ csrc,
                                                  const int* __restrict__ rowptr,
                                                  const float* __restrict__ el,
                                                  const float* __restrict__ er,
                                                  const unsigned short* __restrict__ feat,
                                                  const float* __restrict__ bias,
                                                  unsigned short* __restrict__ rst, int N_) {
    int gw = blockIdx.x * 4 + (threadIdx.x >> 6);
    int lane = threadIdx.x & 63;
    if (gw >= N_) return;
    int r0 = rowptr[gw], r1 = rowptr[gw + 1];
    float erd = er[gw];
    int half = lane >> 5, hl = lane & 31;
    float a0 = 0.f, a1 = 0.f, a2 = 0.f, a3 = 0.f, lsum = 0.f;
    for (int base = r0; base < r1; base += 64) {
        int i = base + lane;
        float ex = 0.f;
        int s = 0;
        if (i < r1) {
            s = csrc[i];
            float v = el[s] + erd;
            v = v > 0.f ? v : NEG_SLOPE * v;
            ex = expf(v - SM_SHIFT);   // softmax shift-invariant; |v| << 80
        }
        lsum += ex;
        int cntc = min(64, r1 - base);
        int j = 0;
        // 4 pairs (8 edges) unrolled: all jj = j..j+7 in range
        for (; j + 7 < cntc; j += 8) {
#pragma unroll
            for (int p = 0; p < 4; ++p) {
                int jj = j + 2 * p + half;
                float exj = __shfl(ex, jj);
                int sj = __shfl(s, jj);
                uintv2 fv = *(const uintv2*)(feat + (size_t)sj * D + hl * 4);
                a0 += bf2f((unsigned short)(fv[0] & 0xffffu)) * exj;
                a1 += bf2f((unsigned short)(fv[0] >> 16)) * exj;
                a2 += bf2f((unsigned short)(fv[1] & 0xffffu)) * exj;
                a3 += bf2f((unsigned short)(fv[1] >> 16)) * exj;
            }
        }
        // tail pairs with guard
        for (; j < cntc; j += 2) {
            int jj = j + half;
            int jjc = jj & 63;
            float exj = __shfl(ex, jjc);
            int sj = __shfl(s, jjc);
            if (jj >= cntc) exj = 0.f;
            uintv2 fv = *(const uintv2*)(feat + (size_t)sj * D + hl * 4);
            a0 += bf2f((unsigned short)(fv[0] & 0xffffu)) * exj;
            a1 += bf2f((unsigned short)(fv[0] >> 16)) * exj;
            a2 += bf2f((unsigned short)(fv[1] & 0xffffu)) * exj;
            a3 += bf2f((unsigned short)(fv[1] >> 16)) * exj;
        }
    }
#pragma unroll
    for (int off = 32; off; off >>= 1) lsum += __shfl_xor(lsum, off);
    // merge even/odd halves
    a0 += __shfl_xor(a0, 32);
    a1 += __shfl_xor(a1, 32);
    a2 += __shfl_xor(a2, 32);
    a3 += __shfl_xor(a3, 32);
    if (half == 0) {
        float inv = (r1 > r0) ? 1.f / lsum : 0.f;
        int cb = hl * 4;
        float v0 = a0 * inv + bias[cb + 0];
        float v1 = a1 * inv + bias[cb + 1];
        float v2 = a2 * inv + bias[cb + 2];
        float v3 = a3 * inv + bias[cb + 3];
        uintv2 pk;
        pk[0] = (unsigned int)f2bf(v0) | ((unsigned int)f2bf(v1) << 16);
        pk[1] = (unsigned int)f2bf(v2) | ((unsigned int)f2bf(v3) << 16);
        *(uintv2*)(rst + (size_t)gw * D + cb) = pk;
    }
}

// ---- LSTM via MFMA; block-level h1/c1 tiles; full-row NT stores ----
#define LM 32
__global__ __launch_bounds__(512) void lstm_mfma_kernel(const unsigned short* __restrict__ x2,
                                                        const float* __restrict__ h0,
                                                        const float* __restrict__ c0,
                                                        const unsigned short* __restrict__ WTb,
                                                        const float* __restrict__ b_ih,
                                                        const float* __restrict__ b_hh,
                                                        float* __restrict__ out, int N_) {
    __shared__ __align__(16) char smem[34560];
    unsigned short (*xb)[264] = reinterpret_cast<unsigned short(*)[264]>(smem);
    float (*th)[132] = reinterpret_cast<float(*)[132]>(smem);
    float (*tc)[132] = reinterpret_cast<float(*)[132]>(smem + 17664);

    int tid = threadIdx.x;
    int w = tid >> 6, l = tid & 63;   // w = 0..7
    int bn = blockIdx.x * LM;
    int cl = l & 15, kg = l >> 4;
    int col = w * 16 + cl;

    float c0r[2][4];
#pragma unroll
    for (int m = 0; m < 2; ++m)
#pragma unroll
        for (int r = 0; r < 4; ++r) {
            int gn = bn + m * 16 + (kg << 2) + r;
            c0r[m][r] = (gn < N_) ? c0[(size_t)gn * D + col] : 0.f;
        }
    float bi  = b_ih[col]       + b_hh[col];
    float bff = b_ih[128 + col] + b_hh[128 + col];
    float bg  = b_ih[256 + col] + b_hh[256 + col];
    float bo  = b_ih[384 + col] + b_hh[384 + col];

    for (int idx = tid; idx < LM * 32; idx += 512) {
        int n = idx >> 5, q = idx & 31;
        int gn = bn + n;
        ushort8v u = (ushort8v)0;
        if (gn < N_) {
            if (q < 16) {
                u = *(const ushort8v*)(x2 + (size_t)gn * D + q * 8);
            } else {
                const float* sp = h0 + (size_t)gn * D + (q - 16) * 8;
                float4 a = ((const float4*)sp)[0];
                float4 b = ((const float4*)sp)[1];
                u[0] = f2bf(a.x); u[1] = f2bf(a.y); u[2] = f2bf(a.z); u[3] = f2bf(a.w);
                u[4] = f2bf(b.x); u[5] = f2bf(b.y); u[6] = f2bf(b.z); u[7] = f2bf(b.w);
            }
        }
        *(ushort8v*)&xb[n][q * 8] = u;
    }
    __syncthreads();

    f32x4 acc[2][4];
#pragma unroll
    for (int m = 0; m < 2; ++m)
#pragma unroll
        for (int g4 = 0; g4 < 4; ++g4) acc[m][g4] = (f32x4)0.f;
    int ak = kg << 3;
#pragma unroll
    for (int ks = 0; ks < 8; ++ks) {
        bf16x8 a0 = *(const bf16x8*)&xb[cl][ks * 32 + ak];
        bf16x8 a1 = *(const bf16x8*)&xb[16 + cl][ks * 32 + ak];
#pragma unroll
        for (int g4 = 0; g4 < 4; ++g4) {
            int ct = g4 * 8 + w;
            bf16x8 b = *(const bf16x8*)(WTb + ((size_t)(ct * 8 + ks) * 64 + l) * 8);
            acc[0][g4] = __builtin_amdgcn_mfma_f32_16x16x32_bf16(a0, b, acc[0][g4], 0, 0, 0);
            acc[1][g4] = __builtin_amdgcn_mfma_f32_16x16x32_bf16(a1, b, acc[1][g4], 0, 0, 0);
        }
    }
    __syncthreads();  // all waves done reading xb; repurpose as th/tc

#pragma unroll
    for (int m = 0; m < 2; ++m)
#pragma unroll
        for (int r = 0; r < 4; ++r) {
            int row = m * 16 + (kg << 2) + r;
            float iv = acc[m][0][r] + bi;
            float fv = acc[m][1][r] + bff;
            float gv = acc[m][2][r] + bg;
            float ov = acc[m][3][r] + bo;
            float c1 = fsig(fv) * c0r[m][r] + fsig(iv) * ftanh(gv);
            float h1 = fsig(ov) * ftanh(c1);
            th[row][col] = h1;
            tc[row][col] = c1;
        }
    __syncthreads();
    size_t NO = (size_t)N_ * D;
#pragma unroll
    for (int t = 0; t < 2; ++t) {
        int idx = t * 512 + tid;
        int row = idx >> 5, q = idx & 31;
        int gn = bn + row;
        if (gn < N_) {
            f32x4 hv = *(const f32x4*)&th[row][q * 4];
            f32x4 cv = *(const f32x4*)&tc[row][q * 4];
            size_t base = (size_t)gn * D + q * 4;
            __builtin_nontemporal_store(hv, (f32x4*)&out[base]);
            __builtin_nontemporal_store(hv, (f32x4*)&out[NO + base]);
            __builtin_nontemporal_store(cv, (f32x4*)&out[2 * NO + base]);
        }
    }
}

extern "C" void kernel_launch(void* const* d_in, const int* in_sizes, int n_in,
                              void* d_out, int out_size, void* d_ws, size_t ws_size,
                              hipStream_t stream) {
    const float* x      = (const float*)d_in[0];
    const float* h      = (const float*)d_in[1];
    const float* c      = (const float*)d_in[2];
    const int*   src0   = (const int*)d_in[3];
    const int*   dst0   = (const int*)d_in[4];
    const int*   src1   = (const int*)d_in[5];
    const int*   dst1   = (const int*)d_in[6];
    const float* W      = (const float*)d_in[7];
    const float* attn_l = (const float*)d_in[8];
    const float* attn_r = (const float*)d_in[9];
    const float* gbias  = (const float*)d_in[10];
    const float* W_ih   = (const float*)d_in[11];
    const float* W_hh   = (const float*)d_in[12];
    const float* b_ih   = (const float*)d_in[13];
    const float* b_hh   = (const float*)d_in[14];
    float* out = (float*)d_out;

    const int N_ = in_sizes[1] / D;  // h is (1,N,128)
    const int E_ = in_sizes[3];
    const int n2 = 2 * N_;
    const int nbuck = (n2 + (1 << CSH) - 1) >> CSH;

    // ---- transients carved out of d_out (3*N*D*4 = 153.6MB) ----
    char* ob = (char*)d_out;
    size_t ooff = 0;
    auto oalloc = [&](size_t nbytes) {
        void* p = ob + ooff;
        ooff += (nbytes + 255) & ~(size_t)255;
        return p;
    };
    unsigned short* featb = (unsigned short*)oalloc((size_t)N_ * D * 2);  // 25.6MB
    float* el   = (float*)oalloc((size_t)N_ * 4);
    float* er   = (float*)oalloc((size_t)N_ * 4);
    int*   rp01 = (int*)oalloc((size_t)(n2 + 1) * 4);
    int*   cs01 = (int*)oalloc((size_t)2 * E_ * 4);                  // 12.8MB
    unsigned int* pbuf = (unsigned int*)oalloc((size_t)2 * E_ * 4);  // 12.8MB
    int*   bcnt  = (int*)oalloc((size_t)1024 * 4);
    int*   bbase = (int*)oalloc((size_t)1024 * 4);
    int*   bcur  = (int*)oalloc((size_t)1024 * 4);

    // ---- d_ws: rst bf16 + swizzled weights ----
    char* wsb = (char*)d_ws;
    size_t off = 0;
    auto alloc = [&](size_t nbytes) {
        void* p = wsb + off;
        off += (nbytes + 255) & ~(size_t)255;
        return p;
    };
    unsigned short* rst  = (unsigned short*)alloc((size_t)N_ * D * 2);
    unsigned short* WTb  = (unsigned short*)alloc((size_t)32 * 8 * 64 * 8 * 2);
    unsigned short* Wswz = (unsigned short*)alloc((size_t)8 * 4 * 64 * 8 * 2);
    (void)ws_size;

    const int featBlocks = (N_ + FM - 1) / FM;
    const int aggBlocks  = (N_ + 3) / 4;
    const int lstmBlocks = (N_ + LM - 1) / LM;
    const int paBlocks   = (2 * E_ + PA_CHUNK - 1) / PA_CHUNK;

    wprep_feat_kernel<<<8, 256, 0, stream>>>(W, Wswz);
    wprep_lstm_kernel<<<64, 256, 0, stream>>>(W_ih, W_hh, WTb);

    // ---- CSR build: bucket hist + 391-scan + multi-split + fused node sort ----
    zero_kernel<<<4, 256, 0, stream>>>(bcnt, 1024);
    bhist_kernel<<<paBlocks, 256, 0, stream>>>(dst0, dst1, bcnt, E_, N_, nbuck);
    bscan_kernel<<<1, 256, 0, stream>>>(bcnt, bbase, bcur, nbuck, 2 * E_);
    partA_kernel<<<paBlocks, 256, 0, stream>>>(src0, src1, dst0, dst1, bcur, pbuf, E_, N_, nbuck);
    partB2_kernel<<<nbuck, 256, 0, stream>>>(pbuf, bbase, rp01, cs01, n2, 2 * E_);

    // ---- two GAT layers ----
    for (int L = 0; L < 2; ++L) {
        if (L == 0)
            feat_mfma_kernel<false><<<featBlocks, 256, 0, stream>>>(x, Wswz, featb,
                                                                    attn_l, attn_r, el, er, N_);
        else
            feat_mfma_kernel<true><<<featBlocks, 256, 0, stream>>>(rst, Wswz, featb,
                                                                   attn_l, attn_r, el, er, N_);
        agg_kernel<<<aggBlocks, 256, 0, stream>>>(cs01, rp01 + (size_t)L * N_, el, er,
                                                  featb, gbias, rst, N_);
    }

    lstm_mfma_kernel<<<lstmBlocks, 512, 0, stream>>>(rst, h, c, WTb, b_ih, b_hh, out, N_);
}

// Round 21
// 370.493 us; speedup vs baseline: 1.0250x; 1.0250x over previous
//
#include <hip/hip_runtime.h>

// GeniePath: 2x GAT(H=1,D=128) + LSTM step. N=100000, E=1600000, D=OUT=128.
// Inputs f32, output f32: [h1 (N*128)] [h1 (N*128)] [c1 (N*128)]
//
// Round 20->21: revert agg to the round-18 proven form (full-wave, 4x
// unrolled gather) - half-wave variant was neutral (gather-latency-bound,
// not issue-bound). Keep round-19 lstm (block-level h1/c1 tiles, full-row
// NT stores: 150MB writes, 58% occupancy).
//
// d_ws: rst bf16 (25.6MB) + WTb (256KB) + Wswz (32KB).
// d_out (153.6MB) holds transients, all dead before lstm_mfma rewrites it.

#define D 128
#define NEG_SLOPE 0.2f
#define SM_SHIFT 8.0f
#define CSH 9            // coarse bucket = node >> CSH (512 nodes)
#define SRCB 18          // src bits in packed pair (N <= 262144)
#define PA_CHUNK 16384

typedef short bf16x8 __attribute__((ext_vector_type(8)));
typedef float f32x4 __attribute__((ext_vector_type(4)));
typedef unsigned short ushort8v __attribute__((ext_vector_type(8)));

__device__ __forceinline__ unsigned short f2bf(float x) {
    unsigned int b = __float_as_uint(x);
    b += 0x7fff + ((b >> 16) & 1);
    return (unsigned short)(b >> 16);
}
__device__ __forceinline__ float bf2f(unsigned short u) {
    union { unsigned int i; float f; } x;
    x.i = ((unsigned int)u) << 16;
    return x.f;
}
__device__ __forceinline__ float fsig(float x) {
    return 1.f / (1.f + __expf(-x));
}
__device__ __forceinline__ float ftanh(float x) {
    x = fminf(15.f, fmaxf(-15.f, x));
    float t = __expf(2.f * x);
    return (t - 1.f) / (t + 1.f);
}

// ---------------- weight swizzles ----------------
__global__ void wprep_feat_kernel(const float* __restrict__ W,
                                  unsigned short* __restrict__ Wswz) {
    int t = blockIdx.x * 256 + threadIdx.x;
    if (t >= 8 * 4 * 64) return;
    int ct = t >> 8, ks = (t >> 6) & 3, lane = t & 63;
    int col = ct * 16 + (lane & 15);
    int k0 = ks * 32 + ((lane >> 4) << 3);
#pragma unroll
    for (int i = 0; i < 8; ++i)
        Wswz[(size_t)t * 8 + i] = f2bf(W[(k0 + i) * D + col]);
}

__global__ void wprep_lstm_kernel(const float* __restrict__ W_ih,
                                  const float* __restrict__ W_hh,
                                  unsigned short* __restrict__ WTb) {
    int t = blockIdx.x * 256 + threadIdx.x;
    if (t >= 32 * 8 * 64) return;
    int ct = t >> 9, ks = (t >> 6) & 7, lane = t & 63;
    int col = ct * 16 + (lane & 15);
    int k0 = ks * 32 + ((lane >> 4) << 3);
#pragma unroll
    for (int i = 0; i < 8; ++i) {
        int k = k0 + i;
        float v = (k < 128) ? W_ih[col * 128 + k] : W_hh[col * 128 + (k - 128)];
        WTb[(size_t)t * 8 + i] = f2bf(v);
    }
}

// ---- feat = x @ W via MFMA; bf16 out; fused el/er ----
#define FM 32
template <bool BF>
__global__ __launch_bounds__(256) void feat_mfma_kernel(const void* __restrict__ xin_,
                                                        const unsigned short* __restrict__ Wswz,
                                                        unsigned short* __restrict__ feat,
                                                        const float* __restrict__ al,
                                                        const float* __restrict__ ar,
                                                        float* __restrict__ el,
                                                        float* __restrict__ er, int N_) {
    __shared__ unsigned short sm[FM][136];
    int tid = threadIdx.x;
    int bn = blockIdx.x * FM;
    for (int idx = tid; idx < FM * 16; idx += 256) {
        int n = idx >> 4, q = idx & 15;
        int gn = bn + n;
        ushort8v u = (ushort8v)0;
        if (gn < N_) {
            if constexpr (BF) {
                u = *(const ushort8v*)((const unsigned short*)xin_ + (size_t)gn * D + q * 8);
            } else {
                const float* sp = (const float*)xin_ + (size_t)gn * D + q * 8;
                float4 a = ((const float4*)sp)[0];
                float4 b = ((const float4*)sp)[1];
                u[0] = f2bf(a.x); u[1] = f2bf(a.y); u[2] = f2bf(a.z); u[3] = f2bf(a.w);
                u[4] = f2bf(b.x); u[5] = f2bf(b.y); u[6] = f2bf(b.z); u[7] = f2bf(b.w);
            }
        }
        *(ushort8v*)&sm[n][q * 8] = u;
    }
    __syncthreads();
    int w = tid >> 6, l = tid & 63;
    f32x4 acc[2][2];
#pragma unroll
    for (int m = 0; m < 2; ++m)
#pragma unroll
        for (int p = 0; p < 2; ++p) acc[m][p] = (f32x4)0.f;
    int ar_ = l & 15, ak = (l >> 4) << 3;
#pragma unroll
    for (int ks = 0; ks < 4; ++ks) {
        bf16x8 a0 = *(const bf16x8*)&sm[ar_][ks * 32 + ak];
        bf16x8 a1 = *(const bf16x8*)&sm[16 + ar_][ks * 32 + ak];
#pragma unroll
        for (int p = 0; p < 2; ++p) {
            int ct = w * 2 + p;
            bf16x8 b = *(const bf16x8*)(Wswz + ((size_t)(ct * 4 + ks) * 64 + l) * 8);
            acc[0][p] = __builtin_amdgcn_mfma_f32_16x16x32_bf16(a0, b, acc[0][p], 0, 0, 0);
            acc[1][p] = __builtin_amdgcn_mfma_f32_16x16x32_bf16(a1, b, acc[1][p], 0, 0, 0);
        }
    }
    __syncthreads();
#pragma unroll
    for (int p = 0; p < 2; ++p) {
        int col = (w * 2 + p) * 16 + (l & 15);
#pragma unroll
        for (int m = 0; m < 2; ++m)
#pragma unroll
            for (int r = 0; r < 4; ++r) {
                int row = m * 16 + ((l >> 4) << 2) + r;
                sm[row][col] = f2bf(acc[m][p][r]);
            }
    }
    __syncthreads();
#pragma unroll
    for (int s = 0; s < 2; ++s) {
        int idx = tid + s * 256;
        int row = idx >> 4, q = idx & 15;
        int gn = bn + row;
        if (gn < N_)
            *(ushort8v*)(feat + (size_t)gn * D + q * 8) = *(const ushort8v*)&sm[row][q * 8];
    }
    {
        int row = w * 8 + (l >> 3);
        int c0 = (l & 7) * 16;
        int gn = bn + row;
        float pl = 0.f, pr = 0.f;
#pragma unroll
        for (int i = 0; i < 16; ++i) {
            float v = bf2f(sm[row][c0 + i]);
            pl += v * al[c0 + i];
            pr += v * ar[c0 + i];
        }
        pl += __shfl_xor(pl, 1); pr += __shfl_xor(pr, 1);
        pl += __shfl_xor(pl, 2); pr += __shfl_xor(pr, 2);
        pl += __shfl_xor(pl, 4); pr += __shfl_xor(pr, 4);
        if ((l & 7) == 0 && gn < N_) { el[gn] = pl; er[gn] = pr; }
    }
}

// ---------------- bucket-level CSR build ----------------
__global__ void zero_kernel(int* __restrict__ p, int n) {
    int i = blockIdx.x * 256 + threadIdx.x;
    if (i < n) p[i] = 0;
}

__global__ __launch_bounds__(256) void bhist_kernel(const int* __restrict__ dst0,
                                                    const int* __restrict__ dst1,
                                                    int* __restrict__ bcnt,
                                                    int E_, int N_, int nbuck) {
    __shared__ int cL[512];
    int tid = threadIdx.x;
    int c0 = blockIdx.x * PA_CHUNK;
    int e2 = 2 * E_;
    int cend = min(c0 + PA_CHUNK, e2);
    for (int t = tid; t < nbuck; t += 256) cL[t] = 0;
    __syncthreads();
    for (int i = c0 + tid; i < cend; i += 256) {
        int d = (i < E_) ? dst0[i] : (dst1[i - E_] + N_);
        atomicAdd(&cL[d >> CSH], 1);
    }
    __syncthreads();
    for (int t = tid; t < nbuck; t += 256) {
        int c = cL[t];
        if (c > 0) atomicAdd(&bcnt[t], c);
    }
}

__global__ __launch_bounds__(256) void bscan_kernel(const int* __restrict__ bcnt,
                                                    int* __restrict__ bbase,
                                                    int* __restrict__ bcur,
                                                    int nbuck, int e2) {
    __shared__ int sarr[256];
    int t = threadIdx.x;
    int v0 = (2 * t < nbuck) ? bcnt[2 * t] : 0;
    int v1 = (2 * t + 1 < nbuck) ? bcnt[2 * t + 1] : 0;
    sarr[t] = v0 + v1;
    __syncthreads();
    for (int off = 1; off < 256; off <<= 1) {
        int x = (t >= off) ? sarr[t - off] : 0;
        __syncthreads();
        sarr[t] += x;
        __syncthreads();
    }
    int excl = sarr[t] - (v0 + v1);
    if (2 * t < nbuck)     { bbase[2 * t] = excl;         bcur[2 * t] = excl; }
    if (2 * t + 1 < nbuck) { bbase[2 * t + 1] = excl + v0; bcur[2 * t + 1] = excl + v0; }
    if (t == 0) bbase[nbuck] = e2;
}

__global__ __launch_bounds__(256) void partA_kernel(const int* __restrict__ src0,
                                                    const int* __restrict__ src1,
                                                    const int* __restrict__ dst0,
                                                    const int* __restrict__ dst1,
                                                    int* __restrict__ bcur,
                                                    unsigned int* __restrict__ pbuf,
                                                    int E_, int N_, int nbuck) {
    __shared__ int cntL[512];
    __shared__ int baseL[512];
    int tid = threadIdx.x;
    int c0 = blockIdx.x * PA_CHUNK;
    int e2 = 2 * E_;
    int cend = min(c0 + PA_CHUNK, e2);
    for (int t = tid; t < nbuck; t += 256) cntL[t] = 0;
    __syncthreads();
    for (int i = c0 + tid; i < cend; i += 256) {
        int d = (i < E_) ? dst0[i] : (dst1[i - E_] + N_);
        atomicAdd(&cntL[d >> CSH], 1);
    }
    __syncthreads();
    for (int t = tid; t < nbuck; t += 256) {
        int c = cntL[t];
        baseL[t] = (c > 0) ? atomicAdd(&bcur[t], c) : 0;
        cntL[t] = 0;
    }
    __syncthreads();
    for (int i = c0 + tid; i < cend; i += 256) {
        int s, d;
        if (i < E_) { s = src0[i]; d = dst0[i]; }
        else        { s = src1[i - E_]; d = dst1[i - E_] + N_; }
        int bin = d >> CSH;
        int loc = atomicAdd(&cntL[bin], 1);
        pbuf[baseL[bin] + loc] = ((unsigned int)(d & ((1 << CSH) - 1)) << SRCB) | (unsigned int)s;
    }
}

__global__ __launch_bounds__(256) void partB2_kernel(const unsigned int* __restrict__ pbuf,
                                                     const int* __restrict__ bbase,
                                                     int* __restrict__ rowptr,
                                                     int* __restrict__ csrc,
                                                     int n2, int e2) {
    __shared__ int histL[1 << CSH];
    __shared__ int sarr[256];
    int b = blockIdx.x;
    int tid = threadIdx.x;
    int bstart = b << CSH;
    int nn = min(1 << CSH, n2 - bstart);
    int r0 = bbase[b], r1 = bbase[b + 1];
    for (int t = tid; t < nn; t += 256) histL[t] = 0;
    __syncthreads();
    for (int i = r0 + tid; i < r1; i += 256)
        atomicAdd(&histL[pbuf[i] >> SRCB], 1);
    __syncthreads();
    int v0 = (2 * tid < nn) ? histL[2 * tid] : 0;
    int v1 = (2 * tid + 1 < nn) ? histL[2 * tid + 1] : 0;
    sarr[tid] = v0 + v1;
    __syncthreads();
    for (int off = 1; off < 256; off <<= 1) {
        int x = (tid >= off) ? sarr[tid - off] : 0;
        __syncthreads();
        sarr[tid] += x;
        __syncthreads();
    }
    int excl = sarr[tid] - (v0 + v1);
    int p0 = r0 + excl, p1 = r0 + excl + v0;
    if (2 * tid < nn)     rowptr[bstart + 2 * tid] = p0;
    if (2 * tid + 1 < nn) rowptr[bstart + 2 * tid + 1] = p1;
    if (b == gridDim.x - 1 && tid == 0) rowptr[n2] = e2;
    __syncthreads();
    if (2 * tid < nn)     histL[2 * tid] = p0;
    if (2 * tid + 1 < nn) histL[2 * tid + 1] = p1;
    __syncthreads();
    for (int i = r0 + tid; i < r1; i += 256) {
        unsigned int pk = pbuf[i];
        int dl = (int)(pk >> SRCB);
        int s = (int)(pk & ((1u << SRCB) - 1));
        int pos = atomicAdd(&histL[dl], 1);
        csrc[pos] = s;
    }
}

// ---- fused softmax + aggregation: single pass, gather unrolled 4x ----
__global__ __launch_bounds__(256) void agg_kernel(const int* __restrict__ csrc,
                                                  const int* __restrict__ rowptr,
                                                  const float* __restrict__ el,
                                                  const float* __restrict__ er,
                                                  const unsigned short* __restrict__ feat,
                                                  const float* __restrict__ bias,
                                                  unsigned short* __restrict__ rst, int N_) {
    int gw = blockIdx.x * 4 + (threadIdx.x >> 6);
    int lane = threadIdx.x & 63;
    if (gw >= N_) return;
    int r0 = rowptr[gw], r1 = rowptr[gw + 1];
    float erd = er[gw];
    float acc0 = 0.f, acc1 = 0.f, lsum = 0.f;
    for (int base = r0; base < r1; base += 64) {
        int i = base + lane;
        float ex = 0.f;
        int s = 0;
        if (i < r1) {
            s = csrc[i];
            float v = el[s] + erd;
            v = v > 0.f ? v : NEG_SLOPE * v;
            ex = expf(v - SM_SHIFT);   // softmax shift-invariant; |v| << 80
        }
        lsum += ex;
        int cntc = min(64, r1 - base);
        int j = 0;
        for (; j + 3 < cntc; j += 4) {
            float e0 = __shfl(ex, j),     e1 = __shfl(ex, j + 1);
            float e2 = __shfl(ex, j + 2), e3 = __shfl(ex, j + 3);
            int   s0 = __shfl(s, j),      s1 = __shfl(s, j + 1);
            int   s2 = __shfl(s, j + 2),  s3 = __shfl(s, j + 3);
            unsigned int f0 = *(const unsigned int*)(feat + (size_t)s0 * D + 2 * lane);
            unsigned int f1 = *(const unsigned int*)(feat + (size_t)s1 * D + 2 * lane);
            unsigned int f2 = *(const unsigned int*)(feat + (size_t)s2 * D + 2 * lane);
            unsigned int f3 = *(const unsigned int*)(feat + (size_t)s3 * D + 2 * lane);
            acc0 += bf2f((unsigned short)(f0 & 0xffffu)) * e0;
            acc1 += bf2f((unsigned short)(f0 >> 16)) * e0;
            acc0 += bf2f((unsigned short)(f1 & 0xffffu)) * e1;
            acc1 += bf2f((unsigned short)(f1 >> 16)) * e1;
            acc0 += bf2f((unsigned short)(f2 & 0xffffu)) * e2;
            acc1 += bf2f((unsigned short)(f2 >> 16)) * e2;
            acc0 += bf2f((unsigned short)(f3 & 0xffffu)) * e3;
            acc1 += bf2f((unsigned short)(f3 >> 16)) * e3;
        }
        for (; j < cntc; ++j) {
            float exj = __shfl(ex, j);
            int sj = __shfl(s, j);
            unsigned int fv = *(const unsigned int*)(feat + (size_t)sj * D + 2 * lane);
            acc0 += bf2f((unsigned short)(fv & 0xffffu)) * exj;
            acc1 += bf2f((unsigned short)(fv >> 16)) * exj;
        }
    }
#pragma unroll
    for (int off = 32; off; off >>= 1) lsum += __shfl_xor(lsum, off);
    float inv = (r1 > r0) ? 1.f / lsum : 0.f;
    float v0 = acc0 * inv + bias[2 * lane];
    float v1 = acc1 * inv + bias[2 * lane + 1];
    unsigned int pk = (unsigned int)f2bf(v0) | ((unsigned int)f2bf(v1) << 16);
    *(unsigned int*)(rst + (size_t)gw * D + 2 * lane) = pk;
}

// ---- LSTM via MFMA; block-level h1/c1 tiles; full-row NT stores ----
#define LM 32
__global__ __launch_bounds__(512) void lstm_mfma_kernel(const unsigned short* __restrict__ x2,
                                                        const float* __restrict__ h0,
                                                        const float* __restrict__ c0,
                                                        const unsigned short* __restrict__ WTb,
                                                        const float* __restrict__ b_ih,
                                                        const float* __restrict__ b_hh,
                                                        float* __restrict__ out, int N_) {
    __shared__ __align__(16) char smem[34560];
    unsigned short (*xb)[264] = reinterpret_cast<unsigned short(*)[264]>(smem);
    float (*th)[132] = reinterpret_cast<float(*)[132]>(smem);
    float (*tc)[132] = reinterpret_cast<float(*)[132]>(smem + 17664);

    int tid = threadIdx.x;
    int w = tid >> 6, l = tid & 63;   // w = 0..7
    int bn = blockIdx.x * LM;
    int cl = l & 15, kg = l >> 4;
    int col = w * 16 + cl;

    float c0r[2][4];
#pragma unroll
    for (int m = 0; m < 2; ++m)
#pragma unroll
        for (int r = 0; r < 4; ++r) {
            int gn = bn + m * 16 + (kg << 2) + r;
            c0r[m][r] = (gn < N_) ? c0[(size_t)gn * D + col] : 0.f;
        }
    float bi  = b_ih[col]       + b_hh[col];
    float bff = b_ih[128 + col] + b_hh[128 + col];
    float bg  = b_ih[256 + col] + b_hh[256 + col];
    float bo  = b_ih[384 + col] + b_hh[384 + col];

    for (int idx = tid; idx < LM * 32; idx += 512) {
        int n = idx >> 5, q = idx & 31;
        int gn = bn + n;
        ushort8v u = (ushort8v)0;
        if (gn < N_) {
            if (q < 16) {
                u = *(const ushort8v*)(x2 + (size_t)gn * D + q * 8);
            } else {
                const float* sp = h0 + (size_t)gn * D + (q - 16) * 8;
                float4 a = ((const float4*)sp)[0];
                float4 b = ((const float4*)sp)[1];
                u[0] = f2bf(a.x); u[1] = f2bf(a.y); u[2] = f2bf(a.z); u[3] = f2bf(a.w);
                u[4] = f2bf(b.x); u[5] = f2bf(b.y); u[6] = f2bf(b.z); u[7] = f2bf(b.w);
            }
        }
        *(ushort8v*)&xb[n][q * 8] = u;
    }
    __syncthreads();

    f32x4 acc[2][4];
#pragma unroll
    for (int m = 0; m < 2; ++m)
#pragma unroll
        for (int g4 = 0; g4 < 4; ++g4) acc[m][g4] = (f32x4)0.f;
    int ak = kg << 3;
#pragma unroll
    for (int ks = 0; ks < 8; ++ks) {
        bf16x8 a0 = *(const bf16x8*)&xb[cl][ks * 32 + ak];
        bf16x8 a1 = *(const bf16x8*)&xb[16 + cl][ks * 32 + ak];
#pragma unroll
        for (int g4 = 0; g4 < 4; ++g4) {
            int ct = g4 * 8 + w;
            bf16x8 b = *(const bf16x8*)(WTb + ((size_t)(ct * 8 + ks) * 64 + l) * 8);
            acc[0][g4] = __builtin_amdgcn_mfma_f32_16x16x32_bf16(a0, b, acc[0][g4], 0, 0, 0);
            acc[1][g4] = __builtin_amdgcn_mfma_f32_16x16x32_bf16(a1, b, acc[1][g4], 0, 0, 0);
        }
    }
    __syncthreads();  // all waves done reading xb; repurpose as th/tc

#pragma unroll
    for (int m = 0; m < 2; ++m)
#pragma unroll
        for (int r = 0; r < 4; ++r) {
            int row = m * 16 + (kg << 2) + r;
            float iv = acc[m][0][r] + bi;
            float fv = acc[m][1][r] + bff;
            float gv = acc[m][2][r] + bg;
            float ov = acc[m][3][r] + bo;
            float c1 = fsig(fv) * c0r[m][r] + fsig(iv) * ftanh(gv);
            float h1 = fsig(ov) * ftanh(c1);
            th[row][col] = h1;
            tc[row][col] = c1;
        }
    __syncthreads();
    size_t NO = (size_t)N_ * D;
#pragma unroll
    for (int t = 0; t < 2; ++t) {
        int idx = t * 512 + tid;
        int row = idx >> 5, q = idx & 31;
        int gn = bn + row;
        if (gn < N_) {
            f32x4 hv = *(const f32x4*)&th[row][q * 4];
            f32x4 cv = *(const f32x4*)&tc[row][q * 4];
            size_t base = (size_t)gn * D + q * 4;
            __builtin_nontemporal_store(hv, (f32x4*)&out[base]);
            __builtin_nontemporal_store(hv, (f32x4*)&out[NO + base]);
            __builtin_nontemporal_store(cv, (f32x4*)&out[2 * NO + base]);
        }
    }
}

extern "C" void kernel_launch(void* const* d_in, const int* in_sizes, int n_in,
                              void* d_out, int out_size, void* d_ws, size_t ws_size,
                              hipStream_t stream) {
    const float* x      = (const float*)d_in[0];
    const float* h      = (const float*)d_in[1];
    const float* c      = (const float*)d_in[2];
    const int*   src0   = (const int*)d_in[3];
    const int*   dst0   = (const int*)d_in[4];
    const int*   src1   = (const int*)d_in[5];
    const int*   dst1   = (const int*)d_in[6];
    const float* W      = (const float*)d_in[7];
    const float* attn_l = (const float*)d_in[8];
    const float* attn_r = (const float*)d_in[9];
    const float* gbias  = (const float*)d_in[10];
    const float* W_ih   = (const float*)d_in[11];
    const float* W_hh   = (const float*)d_in[12];
    const float* b_ih   = (const float*)d_in[13];
    const float* b_hh   = (const float*)d_in[14];
    float* out = (float*)d_out;

    const int N_ = in_sizes[1] / D;  // h is (1,N,128)
    const int E_ = in_sizes[3];
    const int n2 = 2 * N_;
    const int nbuck = (n2 + (1 << CSH) - 1) >> CSH;

    // ---- transients carved out of d_out (3*N*D*4 = 153.6MB) ----
    char* ob = (char*)d_out;
    size_t ooff = 0;
    auto oalloc = [&](size_t nbytes) {
        void* p = ob + ooff;
        ooff += (nbytes + 255) & ~(size_t)255;
        return p;
    };
    unsigned short* featb = (unsigned short*)oalloc((size_t)N_ * D * 2);  // 25.6MB
    float* el   = (float*)oalloc((size_t)N_ * 4);
    float* er   = (float*)oalloc((size_t)N_ * 4);
    int*   rp01 = (int*)oalloc((size_t)(n2 + 1) * 4);
    int*   cs01 = (int*)oalloc((size_t)2 * E_ * 4);                  // 12.8MB
    unsigned int* pbuf = (unsigned int*)oalloc((size_t)2 * E_ * 4);  // 12.8MB
    int*   bcnt  = (int*)oalloc((size_t)1024 * 4);
    int*   bbase = (int*)oalloc((size_t)1024 * 4);
    int*   bcur  = (int*)oalloc((size_t)1024 * 4);

    // ---- d_ws: rst bf16 + swizzled weights ----
    char* wsb = (char*)d_ws;
    size_t off = 0;
    auto alloc = [&](size_t nbytes) {
        void* p = wsb + off;
        off += (nbytes + 255) & ~(size_t)255;
        return p;
    };
    unsigned short* rst  = (unsigned short*)alloc((size_t)N_ * D * 2);
    unsigned short* WTb  = (unsigned short*)alloc((size_t)32 * 8 * 64 * 8 * 2);
    unsigned short* Wswz = (unsigned short*)alloc((size_t)8 * 4 * 64 * 8 * 2);
    (void)ws_size;

    const int featBlocks = (N_ + FM - 1) / FM;
    const int aggBlocks  = (N_ + 3) / 4;
    const int lstmBlocks = (N_ + LM - 1) / LM;
    const int paBlocks   = (2 * E_ + PA_CHUNK - 1) / PA_CHUNK;

    wprep_feat_kernel<<<8, 256, 0, stream>>>(W, Wswz);
    wprep_lstm_kernel<<<64, 256, 0, stream>>>(W_ih, W_hh, WTb);

    // ---- CSR build: bucket hist + 391-scan + multi-split + fused node sort ----
    zero_kernel<<<4, 256, 0, stream>>>(bcnt, 1024);
    bhist_kernel<<<paBlocks, 256, 0, stream>>>(dst0, dst1, bcnt, E_, N_, nbuck);
    bscan_kernel<<<1, 256, 0, stream>>>(bcnt, bbase, bcur, nbuck, 2 * E_);
    partA_kernel<<<paBlocks, 256, 0, stream>>>(src0, src1, dst0, dst1, bcur, pbuf, E_, N_, nbuck);
    partB2_kernel<<<nbuck, 256, 0, stream>>>(pbuf, bbase, rp01, cs01, n2, 2 * E_);

    // ---- two GAT layers ----
    for (int L = 0; L < 2; ++L) {
        if (L == 0)
            feat_mfma_kernel<false><<<featBlocks, 256, 0, stream>>>(x, Wswz, featb,
                                                                    attn_l, attn_r, el, er, N_);
        else
            feat_mfma_kernel<true><<<featBlocks, 256, 0, stream>>>(rst, Wswz, featb,
                                                                   attn_l, attn_r, el, er, N_);
        agg_kernel<<<aggBlocks, 256, 0, stream>>>(cs01, rp01 + (size_t)L * N_, el, er,
                                                  featb, gbias, rst, N_);
    }

    lstm_mfma_kernel<<<lstmBlocks, 512, 0, stream>>>(rst, h, c, WTb, b_ih, b_hh, out, N_);
}